// Round 3
// baseline (2060.152 us; speedup 1.0000x reference)
//
#include <hip/hip_runtime.h>

typedef unsigned short ushort_t;
typedef unsigned long long u64_t;
typedef __attribute__((ext_vector_type(8))) __bf16 bf16x8;
typedef __attribute__((ext_vector_type(4))) float f32x4;
typedef __attribute__((ext_vector_type(4))) unsigned int uint4v;

#define T_TOTAL 65536
#define NLAYERS 20
#define OUT_START 2047
#define OUT_W 63489
#define NBLOCKS 512

// workspace layout
// pbf (ushort) at float-offset 0: 20 layers * 24576 + W0 4096 + W1 16384 = 512000 ushorts
#define PBF_PER_LAYER 24576
#define PBF_LAYERS (NLAYERS * PBF_PER_LAYER)        // 491520
#define PBF_TOTAL (PBF_LAYERS + 4096 + 16384)       // 512000 ushorts = 256000 floats
#define H0_OFF 524288
#define HBUF (64 * T_TOTAL)                          // [tau][ch] fp32
#define H1_OFF (H0_OFF + HBUF)
#define BAR_OFF (H1_OFF + HBUF)                      // grid-barrier counter (16B used)

__device__ __forceinline__ ushort_t f2bf(float x) {
    union { float f; unsigned u; } c; c.f = x;
    unsigned u = c.u + 0x7FFFu + ((c.u >> 16) & 1u);   // RNE
    return (ushort_t)(u >> 16);
}

union BF8 { uint4v u4; bf16x8 v; };

__device__ __forceinline__ bf16x8 cvt8(f32x4 a, f32x4 b) {
    union { unsigned u[4]; bf16x8 v; } r;
    r.u[0] = (unsigned)f2bf(a[0]) | ((unsigned)f2bf(a[1]) << 16);
    r.u[1] = (unsigned)f2bf(a[2]) | ((unsigned)f2bf(a[3]) << 16);
    r.u[2] = (unsigned)f2bf(b[0]) | ((unsigned)f2bf(b[1]) << 16);
    r.u[3] = (unsigned)f2bf(b[2]) | ((unsigned)f2bf(b[3]) << 16);
    return r.v;
}

// Hand-rolled grid barrier: monotonic counter (no sense-reversal state), zeroed
// every launch by pack_mfma -> graph-replay-safe. Explicit agent-scope fences:
// release (L2 writeback) before arrive, acquire (L1/L2 invalidate) after spin —
// required because per-XCD L2s are not cross-coherent on MI355X.
__device__ __forceinline__ void gsync(unsigned* bar, unsigned target) {
    __syncthreads();                       // all waves' stores issued & drained (vmcnt0 at barrier)
    if (threadIdx.x == 0) {
        __threadfence();                   // agent release: write back this XCD's L2
        __hip_atomic_fetch_add(bar, 1u, __ATOMIC_RELEASE, __HIP_MEMORY_SCOPE_AGENT);
        while (__hip_atomic_load(bar, __ATOMIC_ACQUIRE, __HIP_MEMORY_SCOPE_AGENT) < target) {
            __builtin_amdgcn_s_sleep(1);
        }
        __threadfence();                   // agent acquire: invalidate L1/L2 before halo reads
    }
    __syncthreads();                       // hold all waves until invalidation done
}

// ---------------------------------------------------------------- pack ALL MFMA weights (bf16, A-fragment order)
__global__ __launch_bounds__(256) void pack_mfma(
    const float* __restrict__ wf, const float* __restrict__ wg,
    const float* __restrict__ wr, const float* __restrict__ wsk,
    const float* __restrict__ w0h, const float* __restrict__ w1h,
    ushort_t* __restrict__ out, unsigned* __restrict__ bar)
{
    int idx = blockIdx.x * 256 + threadIdx.x;
    if (idx == 0) *bar = 0;                // reset grid barrier every launch (replay-safe)
    if (idx >= PBF_TOTAL) return;
    float v;
    if (idx < PBF_LAYERS) {
        int i = idx / PBF_PER_LAYER;
        int r = idx - i * PBF_PER_LAYER;
        if (r < 16384) {                  // gates A (128x128 = [f;g] x [left||right])
            int j = r & 7, l = (r >> 3) & 63, ks = (r >> 9) & 3, mt = r >> 11;
            int m = mt * 16 + (l & 15);
            int k = ks * 32 + ((l >> 4) << 3) + j;
            int o = m & 63, c = k & 63, half = k >> 6;
            const float* src = (m < 64) ? wf : wg;
            v = src[(((i * 64 + o) * 64 + c) << 1) + half];
        } else {                          // rs A (128x64 = [r;s] x c)
            int rr = r - 16384;
            int j = rr & 7, l = (rr >> 3) & 63, ks = (rr >> 9) & 1, mt = rr >> 10;
            int m = mt * 16 + (l & 15);
            int k = ks * 32 + ((l >> 4) << 3) + j;
            v = (m < 64) ? wr[(i * 64 + m) * 64 + k] : wsk[(i * 64 + (m - 64)) * 64 + k];
        }
    } else if (idx < PBF_LAYERS + 4096) { // W0 head (64x64)
        int rr = idx - PBF_LAYERS;
        int j = rr & 7, l = (rr >> 3) & 63, ks = (rr >> 9) & 1, mt = rr >> 10;
        int m = mt * 16 + (l & 15);
        int k = ks * 32 + ((l >> 4) << 3) + j;
        v = w0h[m * 64 + k];
    } else {                              // W1 head (256x64)
        int rr = idx - PBF_LAYERS - 4096;
        int j = rr & 7, l = (rr >> 3) & 63, ks = (rr >> 9) & 1, mt = rr >> 10;
        int m = mt * 16 + (l & 15);
        int k = ks * 32 + ((l >> 4) << 3) + j;
        v = w1h[m * 64 + k];
    }
    out[idx] = f2bf(v);
}

// ---------------------------------------------------------------- fused persistent kernel
// 512 blocks x 256 threads, PLAIN launch (cooperative API appears to be silently
// dropped under the harness's graph capture — R1/R2 bit-identical all-zero-output
// failures). Co-residency by capacity: __launch_bounds__(256,2) caps VGPR at 256
// -> 8 waves/CU -> 2 blocks/CU; LDS 36.9KB -> 4/CU; capacity 512 == grid, and no
// block exits before the first barrier, so all blocks are seated.
// Block owns taus [blk*128, blk*128+128) for ALL layers:
//   - skip_sum accumulated in registers across 20 layers (no global skip traffic)
//   - one grid barrier per layer replaces 20 kernel launch/drain cycles
//   - dead columns (tau < C_i) computed with clamped reads: finite (tanh/sigmoid
//     saturate, h grows linearly+bounded), never read by valid columns
//   - layer 19's H write skipped (dead); output head fused (reads skip from regs)
__global__ __launch_bounds__(256, 2) void wavenet_fused(
    const float* __restrict__ in, const float* __restrict__ w0v, const float* __restrict__ b0v,
    const ushort_t* __restrict__ pbf,
    const float* __restrict__ bf_all, const float* __restrict__ bg_all,
    const float* __restrict__ br_all, const float* __restrict__ bs_all,
    const float* __restrict__ alpha, const float* __restrict__ b_out0,
    const float* __restrict__ b_out1,
    float* __restrict__ HA, float* __restrict__ HB, float* __restrict__ out,
    unsigned* bar)
{
    __shared__ alignas(16) ushort_t ZB[128 * 72];
    __shared__ alignas(16) ushort_t YB[128 * 72];

    const int tid = threadIdx.x;
    const int l = tid & 63, w = tid >> 6;
    const int l15 = l & 15, quad = l >> 4;
    // XCD-chunked swizzle: blockIdx round-robins XCDs; make logical tau-chunks
    // consecutive within an XCD so tau-d halo reads stay in the local L2.
    const int bid = (int)blockIdx.x;
    const int blk = (bid & 7) * 64 + (bid >> 3);
    const int tau0 = blk * 128;
    int tauN[2]; tauN[0] = tau0 + w * 32 + l15; tauN[1] = tauN[0] + 16;

    // ---- init h0 for own chunk: H[tau][ch] = w0[ch]*in[tau] + b0[ch]
    #pragma unroll
    for (int it = 0; it < 8; ++it) {
        int idx = (it << 8) + tid;           // 0..2047 f32x4-slots
        int trow = idx >> 4, c4 = (idx & 15) << 2;
        float x = in[tau0 + trow];
        f32x4 wv = *(const f32x4*)(w0v + c4);
        f32x4 bv = *(const f32x4*)(b0v + c4);
        f32x4 v;
        #pragma unroll
        for (int r = 0; r < 4; ++r) v[r] = fmaf(wv[r], x, bv[r]);
        *(f32x4*)(HA + (tau0 + trow) * 64 + c4) = v;
    }

    f32x4 skip_acc[4][2];
    #pragma unroll
    for (int mt = 0; mt < 4; ++mt)
        #pragma unroll
        for (int nt = 0; nt < 2; ++nt)
            skip_acc[mt][nt] = (f32x4){0.0f, 0.0f, 0.0f, 0.0f};

    float* Hin = HA;
    float* Hout = HB;

    #pragma unroll 1
    for (int i = 0; i < NLAYERS; ++i) {
        gsync(bar, (unsigned)(i + 1) * NBLOCKS);   // covers init before layer 0; inter-layer H dep after

        const int d = 1 << (i >= 10 ? i - 10 : i);
        const ushort_t* PW = pbf + i * PBF_PER_LAYER;
        const float* bfb = bf_all + i * 64;
        const float* bgb = bg_all + i * 64;
        const float* brb = br_all + i * 64;
        const float* bsb = bs_all + i * 64;

        int rL[2]; rL[0] = max(tauN[0] - d, 0); rL[1] = max(tauN[1] - d, 0);

        // ---- gates GEMM, biases folded into accumulator init
        f32x4 acc[8][2];
        #pragma unroll
        for (int mt = 0; mt < 4; ++mt) {
            f32x4 bfv = *(const f32x4*)(bfb + mt * 16 + quad * 4);
            f32x4 bgv = *(const f32x4*)(bgb + mt * 16 + quad * 4);
            acc[mt][0] = bfv; acc[mt][1] = bfv;
            acc[mt + 4][0] = bgv; acc[mt + 4][1] = bgv;
        }

        #pragma unroll
        for (int ks = 0; ks < 4; ++ks) {
            const int chb = (ks & 1) * 32 + quad * 8;
            bf16x8 bfr[2];
            #pragma unroll
            for (int nt = 0; nt < 2; ++nt) {
                int row = (ks < 2) ? rL[nt] : tauN[nt];
                const float* p = Hin + row * 64 + chb;
                f32x4 x0 = *(const f32x4*)p;
                f32x4 x1 = *(const f32x4*)(p + 4);
                bfr[nt] = cvt8(x0, x1);
            }
            #pragma unroll
            for (int mt = 0; mt < 8; ++mt) {
                BF8 af; af.u4 = *(const uint4v*)(PW + (((mt << 2) + ks) * 64 + l) * 8);
                acc[mt][0] = __builtin_amdgcn_mfma_f32_16x16x32_bf16(af.v, bfr[0], acc[mt][0], 0, 0, 0);
                acc[mt][1] = __builtin_amdgcn_mfma_f32_16x16x32_bf16(af.v, bfr[1], acc[mt][1], 0, 0, 0);
            }
        }

        // ---- z = tanh(f)*sigmoid(g) -> ZB
        #pragma unroll
        for (int nt = 0; nt < 2; ++nt) {
            int nloc = w * 32 + nt * 16 + l15;
            #pragma unroll
            for (int mt = 0; mt < 4; ++mt) {
                u64_t pk = 0;
                #pragma unroll
                for (int r = 0; r < 4; ++r) {
                    float f = acc[mt][nt][r];
                    float g = acc[mt + 4][nt][r];
                    float e2 = __expf(2.0f * f);
                    float th = 1.0f - 2.0f / (e2 + 1.0f);
                    float sg = 1.0f / (1.0f + __expf(-g));
                    pk |= (u64_t)f2bf(th * sg) << (r * 16);
                }
                *(u64_t*)(ZB + nloc * 72 + mt * 16 + quad * 4) = pk;
            }
        }
        __syncthreads();   // orders ZB stores before 128-bit ZB reads

        // ---- res/skip GEMM, biases in acc init
        f32x4 acc2[8][2];
        #pragma unroll
        for (int mt = 0; mt < 4; ++mt) {
            f32x4 brv = *(const f32x4*)(brb + mt * 16 + quad * 4);
            f32x4 bsv = *(const f32x4*)(bsb + mt * 16 + quad * 4);
            acc2[mt][0] = brv; acc2[mt][1] = brv;
            acc2[mt + 4][0] = bsv; acc2[mt + 4][1] = bsv;
        }

        const ushort_t* PRS = PW + 16384;
        #pragma unroll
        for (int ks = 0; ks < 2; ++ks) {
            bf16x8 bfr[2];
            #pragma unroll
            for (int nt = 0; nt < 2; ++nt) {
                BF8 t; t.u4 = *(const uint4v*)(ZB + (w * 32 + nt * 16 + l15) * 72 + ks * 32 + quad * 8);
                bfr[nt] = t.v;
            }
            #pragma unroll
            for (int mt = 0; mt < 8; ++mt) {
                BF8 af; af.u4 = *(const uint4v*)(PRS + (((mt << 1) + ks) * 64 + l) * 8);
                acc2[mt][0] = __builtin_amdgcn_mfma_f32_16x16x32_bf16(af.v, bfr[0], acc2[mt][0], 0, 0, 0);
                acc2[mt][1] = __builtin_amdgcn_mfma_f32_16x16x32_bf16(af.v, bfr[1], acc2[mt][1], 0, 0, 0);
            }
        }

        // ---- epilogue: Hout = res + right; skip accumulates in registers
        #pragma unroll
        for (int nt = 0; nt < 2; ++nt) {
            int tau = tauN[nt];
            const float* hb = Hin + tau * 64;
            float* ho = Hout + tau * 64;
            #pragma unroll
            for (int mt = 0; mt < 4; ++mt) {
                int chb = mt * 16 + quad * 4;
                f32x4 h = *(const f32x4*)(hb + chb);
                f32x4 o;
                #pragma unroll
                for (int r = 0; r < 4; ++r) o[r] = acc2[mt][nt][r] + h[r];
                if (i < NLAYERS - 1) *(f32x4*)(ho + chb) = o;
                #pragma unroll
                for (int r = 0; r < 4; ++r) skip_acc[mt][nt][r] += acc2[mt + 4][nt][r];
            }
        }

        float* t = Hin; Hin = Hout; Hout = t;
    }

    // ---- output head (block-local: skip is in registers; no further grid syncs)
    __syncthreads();   // order layer-19 ZB reads before Phase-A ZB overwrite

    // Phase A: Y0 = lrelu_alpha0(skip) -> ZB rows (wave-local)
    #pragma unroll
    for (int nt = 0; nt < 2; ++nt) {
        int nloc = w * 32 + nt * 16 + l15;
        #pragma unroll
        for (int mt = 0; mt < 4; ++mt) {
            f32x4 a = *(const f32x4*)(alpha + mt * 16 + quad * 4);
            u64_t pk = 0;
            #pragma unroll
            for (int r = 0; r < 4; ++r) {
                float x = skip_acc[mt][nt][r];
                x = x > 0.0f ? x : a[r] * x;
                pk |= (u64_t)f2bf(x) << (r * 16);
            }
            *(u64_t*)(ZB + nloc * 72 + mt * 16 + quad * 4) = pk;
        }
    }
    __syncthreads();

    const ushort_t* PW0 = pbf + PBF_LAYERS;
    const ushort_t* PW1 = PW0 + 4096;

    #pragma unroll 1
    for (int nt = 0; nt < 2; ++nt) {
        int nloc = w * 32 + nt * 16 + l15;

        // W0 GEMM (64x64), bias in acc init
        f32x4 acc0[4];
        #pragma unroll
        for (int mt = 0; mt < 4; ++mt) acc0[mt] = *(const f32x4*)(b_out0 + mt * 16 + quad * 4);
        #pragma unroll
        for (int ks = 0; ks < 2; ++ks) {
            BF8 t; t.u4 = *(const uint4v*)(ZB + nloc * 72 + ks * 32 + quad * 8);
            #pragma unroll
            for (int mt = 0; mt < 4; ++mt) {
                BF8 af; af.u4 = *(const uint4v*)(PW0 + (((mt << 1) + ks) * 64 + l) * 8);
                acc0[mt] = __builtin_amdgcn_mfma_f32_16x16x32_bf16(af.v, t.v, acc0[mt], 0, 0, 0);
            }
        }

        // lrelu_alpha1 -> YB (wave-local rows)
        #pragma unroll
        for (int mt = 0; mt < 4; ++mt) {
            f32x4 a = *(const f32x4*)(alpha + 64 + mt * 16 + quad * 4);
            u64_t pk = 0;
            #pragma unroll
            for (int r = 0; r < 4; ++r) {
                float x = acc0[mt][r];
                x = x > 0.0f ? x : a[r] * x;
                pk |= (u64_t)f2bf(x) << (r * 16);
            }
            *(u64_t*)(YB + nloc * 72 + mt * 16 + quad * 4) = pk;
        }
        __syncthreads();

        // W1 GEMM (256x64), bias in acc init
        f32x4 acc1[16];
        #pragma unroll
        for (int mt = 0; mt < 16; ++mt) acc1[mt] = *(const f32x4*)(b_out1 + mt * 16 + quad * 4);
        #pragma unroll
        for (int ks = 0; ks < 2; ++ks) {
            BF8 t; t.u4 = *(const uint4v*)(YB + nloc * 72 + ks * 32 + quad * 8);
            #pragma unroll
            for (int mt = 0; mt < 16; ++mt) {
                BF8 af; af.u4 = *(const uint4v*)(PW1 + (((mt << 1) + ks) * 64 + l) * 8);
                acc1[mt] = __builtin_amdgcn_mfma_f32_16x16x32_bf16(af.v, t.v, acc1[mt], 0, 0, 0);
            }
        }

        int u = tau0 + nloc - OUT_START;
        if (u >= 0) {
            #pragma unroll
            for (int mt = 0; mt < 16; ++mt)
                #pragma unroll
                for (int r = 0; r < 4; ++r)
                    out[(mt * 16 + quad * 4 + r) * OUT_W + u] = acc1[mt][r];
        }
        __syncthreads();
    }
}

// ---------------------------------------------------------------- launch
extern "C" void kernel_launch(void* const* d_in, const int* in_sizes, int n_in,
                              void* d_out, int out_size, void* d_ws, size_t ws_size,
                              hipStream_t stream)
{
    const float* input  = (const float*)d_in[0];
    const float* w0     = (const float*)d_in[1];
    const float* b0     = (const float*)d_in[2];
    const float* wf     = (const float*)d_in[3];
    const float* bf     = (const float*)d_in[4];
    const float* wg     = (const float*)d_in[5];
    const float* bg     = (const float*)d_in[6];
    const float* wr     = (const float*)d_in[7];
    const float* br     = (const float*)d_in[8];
    const float* wsk    = (const float*)d_in[9];
    const float* bs     = (const float*)d_in[10];
    const float* alpha  = (const float*)d_in[11];
    const float* w_out0 = (const float*)d_in[12];
    const float* b_out0 = (const float*)d_in[13];
    const float* w_out1 = (const float*)d_in[14];
    const float* b_out1 = (const float*)d_in[15];
    float* outp = (float*)d_out;

    float* wsbase = (float*)d_ws;
    ushort_t* pbf = (ushort_t*)wsbase;
    float* HA = wsbase + H0_OFF;
    float* HB = wsbase + H1_OFF;
    unsigned* bar = (unsigned*)(wsbase + BAR_OFF);

    pack_mfma<<<PBF_TOTAL / 256, 256, 0, stream>>>(wf, wg, wr, wsk, w_out0, w_out1, pbf, bar);

    wavenet_fused<<<dim3(NBLOCKS), dim3(256), 0, stream>>>(
        input, w0, b0, pbf, bf, bg, br, bs, alpha, b_out0, b_out1,
        HA, HB, outp, bar);
}

// Round 4
// 867.283 us; speedup vs baseline: 2.3754x; 2.3754x over previous
//
#include <hip/hip_runtime.h>

typedef unsigned short ushort_t;
typedef unsigned long long u64_t;
typedef __attribute__((ext_vector_type(8))) __bf16 bf16x8;
typedef __attribute__((ext_vector_type(4))) float f32x4;
typedef __attribute__((ext_vector_type(4))) unsigned int uint4v;

#define T_TOTAL 65536
#define NLAYERS 20
#define OUT_START 2047
#define OUT_W 63489
#define NBLOCKS 512

// workspace layout
// pbf (ushort) at float-offset 0: 20 layers * 24576 + W0 4096 + W1 16384 = 512000 ushorts
#define PBF_PER_LAYER 24576
#define PBF_LAYERS (NLAYERS * PBF_PER_LAYER)        // 491520
#define PBF_TOTAL (PBF_LAYERS + 4096 + 16384)       // 512000 ushorts = 256000 floats
#define H0_OFF 524288
#define HBUF (64 * T_TOTAL)                          // [tau][ch] fp32
#define H1_OFF (H0_OFF + HBUF)
#define FLAG_OFF (H1_OFF + HBUF)                     // 512 flags, 128B apart (64KB)

__device__ __forceinline__ ushort_t f2bf(float x) {
    union { float f; unsigned u; } c; c.f = x;
    unsigned u = c.u + 0x7FFFu + ((c.u >> 16) & 1u);   // RNE
    return (ushort_t)(u >> 16);
}

union BF8 { uint4v u4; bf16x8 v; };

__device__ __forceinline__ bf16x8 cvt8(f32x4 a, f32x4 b) {
    union { unsigned u[4]; bf16x8 v; } r;
    r.u[0] = (unsigned)f2bf(a[0]) | ((unsigned)f2bf(a[1]) << 16);
    r.u[1] = (unsigned)f2bf(a[2]) | ((unsigned)f2bf(a[3]) << 16);
    r.u[2] = (unsigned)f2bf(b[0]) | ((unsigned)f2bf(b[1]) << 16);
    r.u[3] = (unsigned)f2bf(b[2]) | ((unsigned)f2bf(b[3]) << 16);
    return r.v;
}

// ---------------------------------------------------------------- pack ALL MFMA weights (bf16, A-fragment order)
__global__ __launch_bounds__(256) void pack_mfma(
    const float* __restrict__ wf, const float* __restrict__ wg,
    const float* __restrict__ wr, const float* __restrict__ wsk,
    const float* __restrict__ w0h, const float* __restrict__ w1h,
    ushort_t* __restrict__ out, unsigned* __restrict__ flags)
{
    int idx = blockIdx.x * 256 + threadIdx.x;
    if (idx < NBLOCKS) flags[idx << 5] = 0u;   // reset progress flags every launch (replay-safe;
                                               // kernel-boundary release makes this agent-visible)
    if (idx >= PBF_TOTAL) return;
    float v;
    if (idx < PBF_LAYERS) {
        int i = idx / PBF_PER_LAYER;
        int r = idx - i * PBF_PER_LAYER;
        if (r < 16384) {                  // gates A (128x128 = [f;g] x [left||right])
            int j = r & 7, l = (r >> 3) & 63, ks = (r >> 9) & 3, mt = r >> 11;
            int m = mt * 16 + (l & 15);
            int k = ks * 32 + ((l >> 4) << 3) + j;
            int o = m & 63, c = k & 63, half = k >> 6;
            const float* src = (m < 64) ? wf : wg;
            v = src[(((i * 64 + o) * 64 + c) << 1) + half];
        } else {                          // rs A (128x64 = [r;s] x c)
            int rr = r - 16384;
            int j = rr & 7, l = (rr >> 3) & 63, ks = (rr >> 9) & 1, mt = rr >> 10;
            int m = mt * 16 + (l & 15);
            int k = ks * 32 + ((l >> 4) << 3) + j;
            v = (m < 64) ? wr[(i * 64 + m) * 64 + k] : wsk[(i * 64 + (m - 64)) * 64 + k];
        }
    } else if (idx < PBF_LAYERS + 4096) { // W0 head (64x64)
        int rr = idx - PBF_LAYERS;
        int j = rr & 7, l = (rr >> 3) & 63, ks = (rr >> 9) & 1, mt = rr >> 10;
        int m = mt * 16 + (l & 15);
        int k = ks * 32 + ((l >> 4) << 3) + j;
        v = w0h[m * 64 + k];
    } else {                              // W1 head (256x64)
        int rr = idx - PBF_LAYERS - 4096;
        int j = rr & 7, l = (rr >> 3) & 63, ks = (rr >> 9) & 1, mt = rr >> 10;
        int m = mt * 16 + (l & 15);
        int k = ks * 32 + ((l >> 4) << 3) + j;
        v = w1h[m * 64 + k];
    }
    out[idx] = f2bf(v);
}

// ---------------------------------------------------------------- fused persistent kernel
// 512 blocks x 256 threads, plain launch (cooperative API is dropped under graph
// capture — R1/R2). Co-residency by capacity: __launch_bounds__(256,2) caps VGPR
// at 256 -> 8 waves/CU -> 2 blocks/CU; grid == capacity == 512.
//
// R3 lesson: a single global barrier counter cost ~96us/layer (512 RMWs
// serializing on one LLC line under 511 acquire-pollers). Replaced with
// NEIGHBOR PROGRESS FLAGS exploiting the dilation structure: layer i reads at
// most ceil(d_i/128) <= 4 blocks back, and overwrites a buffer read by at most
// ceil(d_{i-1}/128) <= 4 blocks forward. flag[b] = 1 + layers completed
// (1 after init). Before layer i, block b waits flag[b-k] >= i+1 (producers,
// k<=ceil(d_i/128)) and flag[b+k] >= i+1 (anti-dep readers, k<=ceil(d_{i-1}/128)).
// Deadlock-free (diamond deps, skew bound +-1 layer); each flag line has one
// writer (release store, no RMW) and <=8 pollers -> no contention.
__global__ __launch_bounds__(256, 2) void wavenet_fused(
    const float* __restrict__ in, const float* __restrict__ w0v, const float* __restrict__ b0v,
    const ushort_t* __restrict__ pbf,
    const float* __restrict__ bf_all, const float* __restrict__ bg_all,
    const float* __restrict__ br_all, const float* __restrict__ bs_all,
    const float* __restrict__ alpha, const float* __restrict__ b_out0,
    const float* __restrict__ b_out1,
    float* __restrict__ HA, float* __restrict__ HB, float* __restrict__ out,
    unsigned* flags)
{
    __shared__ alignas(16) ushort_t ZB[128 * 72];
    __shared__ alignas(16) ushort_t YB[64 * 72];

    const int tid = threadIdx.x;
    const int l = tid & 63, w = tid >> 6;
    const int l15 = l & 15, quad = l >> 4;
    // XCD-chunked swizzle: blockIdx round-robins XCDs; make logical tau-chunks
    // consecutive within an XCD so tau-d halo reads stay in the local L2.
    const int bid = (int)blockIdx.x;
    const int blk = (bid & 7) * 64 + (bid >> 3);
    const int tau0 = blk * 128;
    int tauN[2]; tauN[0] = tau0 + w * 32 + l15; tauN[1] = tauN[0] + 16;

    // ---- init h0 for own chunk: H[tau][ch] = w0[ch]*in[tau] + b0[ch]
    #pragma unroll
    for (int it = 0; it < 8; ++it) {
        int idx = (it << 8) + tid;           // 0..2047 f32x4-slots
        int trow = idx >> 4, c4 = (idx & 15) << 2;
        float x = in[tau0 + trow];
        f32x4 wv = *(const f32x4*)(w0v + c4);
        f32x4 bv = *(const f32x4*)(b0v + c4);
        f32x4 v;
        #pragma unroll
        for (int r = 0; r < 4; ++r) v[r] = fmaf(wv[r], x, bv[r]);
        *(f32x4*)(HA + (tau0 + trow) * 64 + c4) = v;
    }

    // publish init: flag[blk] = 1 (release: vmcnt drained by syncthreads, wbl2+store by tid 0)
    __syncthreads();
    if (tid == 0)
        __hip_atomic_store(&flags[blk << 5], 1u, __ATOMIC_RELEASE, __HIP_MEMORY_SCOPE_AGENT);

    f32x4 skip_acc[4][2];
    #pragma unroll
    for (int mt = 0; mt < 4; ++mt)
        #pragma unroll
        for (int nt = 0; nt < 2; ++nt)
            skip_acc[mt][nt] = (f32x4){0.0f, 0.0f, 0.0f, 0.0f};

    float* Hin = HA;
    float* Hout = HB;

    #pragma unroll 1
    for (int i = 0; i < NLAYERS; ++i) {
        const int d = 1 << (i >= 10 ? i - 10 : i);
        const int dprev = (i == 0) ? 0 : (1 << ((i - 1) >= 10 ? i - 11 : i - 1));
        const int nleft = (d + 127) >> 7;              // producers needed (<=4)
        const int nright = (dprev + 127) >> 7;         // anti-dep readers (<=4; 0 at i=0)

        // ---- wait for neighbor progress: lanes 0-3 poll left, 4-7 poll right
        if (w == 0) {
            int nb = -1;
            if (l < 4) { int k = l + 1; if (k <= nleft) nb = blk - k; }
            else if (l < 8) { int k = l - 3; if (k <= nright) nb = blk + k; }
            if (nb >= 0 && nb < NBLOCKS) {
                unsigned tgt = (unsigned)(i + 1);
                while (__hip_atomic_load(&flags[nb << 5], __ATOMIC_ACQUIRE,
                                         __HIP_MEMORY_SCOPE_AGENT) < tgt)
                    __builtin_amdgcn_s_sleep(4);
            }
        }
        __syncthreads();   // all waves held until acquire (L1/L2 inv) done

        const ushort_t* PW = pbf + i * PBF_PER_LAYER;
        const float* bfb = bf_all + i * 64;
        const float* bgb = bg_all + i * 64;
        const float* brb = br_all + i * 64;
        const float* bsb = bs_all + i * 64;

        int rL[2]; rL[0] = max(tauN[0] - d, 0); rL[1] = max(tauN[1] - d, 0);

        // ---- gates GEMM, biases folded into accumulator init
        f32x4 acc[8][2];
        #pragma unroll
        for (int mt = 0; mt < 4; ++mt) {
            f32x4 bfv = *(const f32x4*)(bfb + mt * 16 + quad * 4);
            f32x4 bgv = *(const f32x4*)(bgb + mt * 16 + quad * 4);
            acc[mt][0] = bfv; acc[mt][1] = bfv;
            acc[mt + 4][0] = bgv; acc[mt + 4][1] = bgv;
        }

        #pragma unroll
        for (int ks = 0; ks < 4; ++ks) {
            const int chb = (ks & 1) * 32 + quad * 8;
            bf16x8 bfr[2];
            #pragma unroll
            for (int nt = 0; nt < 2; ++nt) {
                int row = (ks < 2) ? rL[nt] : tauN[nt];
                const float* p = Hin + row * 64 + chb;
                f32x4 x0 = *(const f32x4*)p;
                f32x4 x1 = *(const f32x4*)(p + 4);
                bfr[nt] = cvt8(x0, x1);
            }
            #pragma unroll
            for (int mt = 0; mt < 8; ++mt) {
                BF8 af; af.u4 = *(const uint4v*)(PW + (((mt << 2) + ks) * 64 + l) * 8);
                acc[mt][0] = __builtin_amdgcn_mfma_f32_16x16x32_bf16(af.v, bfr[0], acc[mt][0], 0, 0, 0);
                acc[mt][1] = __builtin_amdgcn_mfma_f32_16x16x32_bf16(af.v, bfr[1], acc[mt][1], 0, 0, 0);
            }
        }

        // ---- z = tanh(f)*sigmoid(g) -> ZB
        #pragma unroll
        for (int nt = 0; nt < 2; ++nt) {
            int nloc = w * 32 + nt * 16 + l15;
            #pragma unroll
            for (int mt = 0; mt < 4; ++mt) {
                u64_t pk = 0;
                #pragma unroll
                for (int r = 0; r < 4; ++r) {
                    float f = acc[mt][nt][r];
                    float g = acc[mt + 4][nt][r];
                    float e2 = __expf(2.0f * f);
                    float th = 1.0f - 2.0f / (e2 + 1.0f);
                    float sg = 1.0f / (1.0f + __expf(-g));
                    pk |= (u64_t)f2bf(th * sg) << (r * 16);
                }
                *(u64_t*)(ZB + nloc * 72 + mt * 16 + quad * 4) = pk;
            }
        }
        __syncthreads();   // orders ZB stores before 128-bit ZB reads

        // ---- res/skip GEMM, biases in acc init
        f32x4 acc2[8][2];
        #pragma unroll
        for (int mt = 0; mt < 4; ++mt) {
            f32x4 brv = *(const f32x4*)(brb + mt * 16 + quad * 4);
            f32x4 bsv = *(const f32x4*)(bsb + mt * 16 + quad * 4);
            acc2[mt][0] = brv; acc2[mt][1] = brv;
            acc2[mt + 4][0] = bsv; acc2[mt + 4][1] = bsv;
        }

        const ushort_t* PRS = PW + 16384;
        #pragma unroll
        for (int ks = 0; ks < 2; ++ks) {
            bf16x8 bfr[2];
            #pragma unroll
            for (int nt = 0; nt < 2; ++nt) {
                BF8 t; t.u4 = *(const uint4v*)(ZB + (w * 32 + nt * 16 + l15) * 72 + ks * 32 + quad * 8);
                bfr[nt] = t.v;
            }
            #pragma unroll
            for (int mt = 0; mt < 8; ++mt) {
                BF8 af; af.u4 = *(const uint4v*)(PRS + (((mt << 1) + ks) * 64 + l) * 8);
                acc2[mt][0] = __builtin_amdgcn_mfma_f32_16x16x32_bf16(af.v, bfr[0], acc2[mt][0], 0, 0, 0);
                acc2[mt][1] = __builtin_amdgcn_mfma_f32_16x16x32_bf16(af.v, bfr[1], acc2[mt][1], 0, 0, 0);
            }
        }

        // ---- epilogue: Hout = res + right; skip accumulates in registers
        #pragma unroll
        for (int nt = 0; nt < 2; ++nt) {
            int tau = tauN[nt];
            const float* hb = Hin + tau * 64;
            float* ho = Hout + tau * 64;
            #pragma unroll
            for (int mt = 0; mt < 4; ++mt) {
                int chb = mt * 16 + quad * 4;
                f32x4 h = *(const f32x4*)(hb + chb);
                f32x4 o;
                #pragma unroll
                for (int r = 0; r < 4; ++r) o[r] = acc2[mt][nt][r] + h[r];
                if (i < NLAYERS - 1) *(f32x4*)(ho + chb) = o;
                #pragma unroll
                for (int r = 0; r < 4; ++r) skip_acc[mt][nt][r] += acc2[mt + 4][nt][r];
            }
        }

        // ---- publish layer completion: flag[blk] = i+2 (not needed after last layer)
        __syncthreads();   // drain all waves' Hout stores into L2 (vmcnt0 at barrier)
        if (i < NLAYERS - 1 && tid == 0)
            __hip_atomic_store(&flags[blk << 5], (unsigned)(i + 2), __ATOMIC_RELEASE,
                               __HIP_MEMORY_SCOPE_AGENT);

        float* t = Hin; Hin = Hout; Hout = t;
    }

    // ---- output head (block-local: skip is in registers; no further grid syncs)
    // (the epilogue __syncthreads above already ordered layer-19 ZB reads)

    // Phase A: Y0 = lrelu_alpha0(skip) -> ZB rows (wave-local)
    #pragma unroll
    for (int nt = 0; nt < 2; ++nt) {
        int nloc = w * 32 + nt * 16 + l15;
        #pragma unroll
        for (int mt = 0; mt < 4; ++mt) {
            f32x4 a = *(const f32x4*)(alpha + mt * 16 + quad * 4);
            u64_t pk = 0;
            #pragma unroll
            for (int r = 0; r < 4; ++r) {
                float x = skip_acc[mt][nt][r];
                x = x > 0.0f ? x : a[r] * x;
                pk |= (u64_t)f2bf(x) << (r * 16);
            }
            *(u64_t*)(ZB + nloc * 72 + mt * 16 + quad * 4) = pk;
        }
    }
    __syncthreads();

    const ushort_t* PW0 = pbf + PBF_LAYERS;
    const ushort_t* PW1 = PW0 + 4096;

    #pragma unroll 1
    for (int nt = 0; nt < 2; ++nt) {
        int nloc = w * 32 + nt * 16 + l15;
        int zloc = w * 32 + nt * 16 + l15;

        // W0 GEMM (64x64), bias in acc init
        f32x4 acc0[4];
        #pragma unroll
        for (int mt = 0; mt < 4; ++mt) acc0[mt] = *(const f32x4*)(b_out0 + mt * 16 + quad * 4);
        #pragma unroll
        for (int ks = 0; ks < 2; ++ks) {
            BF8 t; t.u4 = *(const uint4v*)(ZB + zloc * 72 + ks * 32 + quad * 8);
            #pragma unroll
            for (int mt = 0; mt < 4; ++mt) {
                BF8 af; af.u4 = *(const uint4v*)(PW0 + (((mt << 1) + ks) * 64 + l) * 8);
                acc0[mt] = __builtin_amdgcn_mfma_f32_16x16x32_bf16(af.v, t.v, acc0[mt], 0, 0, 0);
            }
        }

        // lrelu_alpha1 -> YB (wave-local rows; YB is 64 rows, indexed w*16+l15)
        int yloc = w * 16 + l15;
        #pragma unroll
        for (int mt = 0; mt < 4; ++mt) {
            f32x4 a = *(const f32x4*)(alpha + 64 + mt * 16 + quad * 4);
            u64_t pk = 0;
            #pragma unroll
            for (int r = 0; r < 4; ++r) {
                float x = acc0[mt][r];
                x = x > 0.0f ? x : a[r] * x;
                pk |= (u64_t)f2bf(x) << (r * 16);
            }
            *(u64_t*)(YB + yloc * 72 + mt * 16 + quad * 4) = pk;
        }
        __syncthreads();

        // W1 GEMM (256x64), bias in acc init
        f32x4 acc1[16];
        #pragma unroll
        for (int mt = 0; mt < 16; ++mt) acc1[mt] = *(const f32x4*)(b_out1 + mt * 16 + quad * 4);
        #pragma unroll
        for (int ks = 0; ks < 2; ++ks) {
            BF8 t; t.u4 = *(const uint4v*)(YB + yloc * 72 + ks * 32 + quad * 8);
            #pragma unroll
            for (int mt = 0; mt < 16; ++mt) {
                BF8 af; af.u4 = *(const uint4v*)(PW1 + (((mt << 1) + ks) * 64 + l) * 8);
                acc1[mt] = __builtin_amdgcn_mfma_f32_16x16x32_bf16(af.v, t.v, acc1[mt], 0, 0, 0);
            }
        }

        int u = tau0 + nloc - OUT_START;
        if (u >= 0) {
            #pragma unroll
            for (int mt = 0; mt < 16; ++mt)
                #pragma unroll
                for (int r = 0; r < 4; ++r)
                    out[(mt * 16 + quad * 4 + r) * OUT_W + u] = acc1[mt][r];
        }
        __syncthreads();
    }
}

// ---------------------------------------------------------------- launch
extern "C" void kernel_launch(void* const* d_in, const int* in_sizes, int n_in,
                              void* d_out, int out_size, void* d_ws, size_t ws_size,
                              hipStream_t stream)
{
    const float* input  = (const float*)d_in[0];
    const float* w0     = (const float*)d_in[1];
    const float* b0     = (const float*)d_in[2];
    const float* wf     = (const float*)d_in[3];
    const float* bf     = (const float*)d_in[4];
    const float* wg     = (const float*)d_in[5];
    const float* bg     = (const float*)d_in[6];
    const float* wr     = (const float*)d_in[7];
    const float* br     = (const float*)d_in[8];
    const float* wsk    = (const float*)d_in[9];
    const float* bs     = (const float*)d_in[10];
    const float* alpha  = (const float*)d_in[11];
    const float* w_out0 = (const float*)d_in[12];
    const float* b_out0 = (const float*)d_in[13];
    const float* w_out1 = (const float*)d_in[14];
    const float* b_out1 = (const float*)d_in[15];
    float* outp = (float*)d_out;

    float* wsbase = (float*)d_ws;
    ushort_t* pbf = (ushort_t*)wsbase;
    float* HA = wsbase + H0_OFF;
    float* HB = wsbase + H1_OFF;
    unsigned* flags = (unsigned*)(wsbase + FLAG_OFF);

    pack_mfma<<<PBF_TOTAL / 256, 256, 0, stream>>>(wf, wg, wr, wsk, w_out0, w_out1, pbf, flags);

    wavenet_fused<<<dim3(NBLOCKS), dim3(256), 0, stream>>>(
        input, w0, b0, pbf, bf, bg, br, bs, alpha, b_out0, b_out1,
        HA, HB, outp, flags);
}

// Round 6
// 531.795 us; speedup vs baseline: 3.8740x; 1.6309x over previous
//
#include <hip/hip_runtime.h>

typedef unsigned short ushort_t;
typedef unsigned long long u64_t;
typedef __attribute__((ext_vector_type(8))) __bf16 bf16x8;
typedef __attribute__((ext_vector_type(4))) float f32x4;
typedef __attribute__((ext_vector_type(4))) unsigned int uint4v;

#define T_TOTAL 65536
#define NLAYERS 20
#define OUT_START 2047
#define OUT_W 63489
#define NBLOCKS 512

// workspace layout
#define PBF_PER_LAYER 24576
#define PBF_LAYERS (NLAYERS * PBF_PER_LAYER)        // 491520
#define PBF_TOTAL (PBF_LAYERS + 4096 + 16384)       // 512000 ushorts = 256000 floats
#define H0_OFF 524288
#define HBUF (64 * T_TOTAL)                          // [tau][ch] fp32
#define H1_OFF (H0_OFF + HBUF)
#define FLAG_OFF (H1_OFF + HBUF)                     // 512 flags, 128B apart (64KB)

__device__ __forceinline__ ushort_t f2bf(float x) {
    union { float f; unsigned u; } c; c.f = x;
    unsigned u = c.u + 0x7FFFu + ((c.u >> 16) & 1u);   // RNE
    return (ushort_t)(u >> 16);
}

union BF8 { uint4v u4; bf16x8 v; };

__device__ __forceinline__ bf16x8 cvt8(f32x4 a, f32x4 b) {
    union { unsigned u[4]; bf16x8 v; } r;
    r.u[0] = (unsigned)f2bf(a[0]) | ((unsigned)f2bf(a[1]) << 16);
    r.u[1] = (unsigned)f2bf(a[2]) | ((unsigned)f2bf(a[3]) << 16);
    r.u[2] = (unsigned)f2bf(b[0]) | ((unsigned)f2bf(b[1]) << 16);
    r.u[3] = (unsigned)f2bf(b[2]) | ((unsigned)f2bf(b[3]) << 16);
    return r.v;
}

// ---------------------------------------------------------------- pack ALL MFMA weights (bf16, A-fragment order)
__global__ __launch_bounds__(256) void pack_mfma(
    const float* __restrict__ wf, const float* __restrict__ wg,
    const float* __restrict__ wr, const float* __restrict__ wsk,
    const float* __restrict__ w0h, const float* __restrict__ w1h,
    ushort_t* __restrict__ out, unsigned* __restrict__ flags)
{
    int idx = blockIdx.x * 256 + threadIdx.x;
    if (idx < NBLOCKS) flags[idx << 5] = 0u;   // reset progress flags every launch (replay-safe;
                                               // kernel-end writeback makes this LLC-visible)
    if (idx >= PBF_TOTAL) return;
    float v;
    if (idx < PBF_LAYERS) {
        int i = idx / PBF_PER_LAYER;
        int r = idx - i * PBF_PER_LAYER;
        if (r < 16384) {                  // gates A (128x128 = [f;g] x [left||right])
            int j = r & 7, l = (r >> 3) & 63, ks = (r >> 9) & 3, mt = r >> 11;
            int m = mt * 16 + (l & 15);
            int k = ks * 32 + ((l >> 4) << 3) + j;
            int o = m & 63, c = k & 63, half = k >> 6;
            const float* src = (m < 64) ? wf : wg;
            v = src[(((i * 64 + o) * 64 + c) << 1) + half];
        } else {                          // rs A (128x64 = [r;s] x c)
            int rr = r - 16384;
            int j = rr & 7, l = (rr >> 3) & 63, ks = (rr >> 9) & 1, mt = rr >> 10;
            int m = mt * 16 + (l & 15);
            int k = ks * 32 + ((l >> 4) << 3) + j;
            v = (m < 64) ? wr[(i * 64 + m) * 64 + k] : wsk[(i * 64 + (m - 64)) * 64 + k];
        }
    } else if (idx < PBF_LAYERS + 4096) { // W0 head (64x64)
        int rr = idx - PBF_LAYERS;
        int j = rr & 7, l = (rr >> 3) & 63, ks = (rr >> 9) & 1, mt = rr >> 10;
        int m = mt * 16 + (l & 15);
        int k = ks * 32 + ((l >> 4) << 3) + j;
        v = w0h[m * 64 + k];
    } else {                              // W1 head (256x64)
        int rr = idx - PBF_LAYERS - 4096;
        int j = rr & 7, l = (rr >> 3) & 63, ks = (rr >> 9) & 1, mt = rr >> 10;
        int m = mt * 16 + (l & 15);
        int k = ks * 32 + ((l >> 4) << 3) + j;
        v = w1h[m * 64 + k];
    }
    out[idx] = f2bf(v);
}

// ---------------------------------------------------------------- fused persistent kernel
// 512 blocks x 256 threads, plain launch. Co-residency by capacity:
// __launch_bounds__(256,2) -> 2 blocks/CU; grid == capacity == 512.
//
// R5 design (fence-free sync): ALL H-buffer accesses use sc1 (device scope:
// bypass L1/L2, served at the LLC — the single coherence point where the flag
// atomics already live). Producer: waitcnt vmcnt(0) -> syncthreads -> RELAXED
// flag store (no wbl2). Consumer: RELAXED poll -> syncthreads -> sc1 loads
// (no inv). No H line is ever in L1/L2 -> no stale-copy hazard; weights stay
// L2-cached across all layers (no invalidation flood).
// R5 crashed on an inline-asm regalloc hazard: multi-instruction load blocks
// MUST use early-clobber ("=&v") outputs, else an output tuple can alias the
// address pair still needed by later loads in the same block -> wild address.
__global__ __launch_bounds__(256, 2) void wavenet_fused(
    const float* __restrict__ in, const float* __restrict__ w0v, const float* __restrict__ b0v,
    const ushort_t* __restrict__ pbf,
    const float* __restrict__ bf_all, const float* __restrict__ bg_all,
    const float* __restrict__ br_all, const float* __restrict__ bs_all,
    const float* __restrict__ alpha, const float* __restrict__ b_out0,
    const float* __restrict__ b_out1,
    float* __restrict__ HA, float* __restrict__ HB, float* __restrict__ out,
    unsigned* flags)
{
    __shared__ alignas(16) ushort_t ZB[128 * 72];
    __shared__ alignas(16) ushort_t YB[64 * 72];

    const int tid = threadIdx.x;
    const int l = tid & 63, w = tid >> 6;
    const int l15 = l & 15, quad = l >> 4;
    const int bid = (int)blockIdx.x;
    const int blk = (bid & 7) * 64 + (bid >> 3);
    const int tau0 = blk * 128;
    int tauN[2]; tauN[0] = tau0 + w * 32 + l15; tauN[1] = tauN[0] + 16;

    // ---- init h0 for own chunk: H[tau][ch] = w0[ch]*in[tau] + b0[ch] (sc1 stores -> LLC)
    #pragma unroll
    for (int it = 0; it < 8; ++it) {
        int idx = (it << 8) + tid;           // 0..2047 f32x4-slots
        int trow = idx >> 4, c4 = (idx & 15) << 2;
        float x = in[tau0 + trow];
        f32x4 wv = *(const f32x4*)(w0v + c4);
        f32x4 bv = *(const f32x4*)(b0v + c4);
        f32x4 v;
        #pragma unroll
        for (int r = 0; r < 4; ++r) v[r] = fmaf(wv[r], x, bv[r]);
        float* dst = HA + (tau0 + trow) * 64 + c4;
        asm volatile("global_store_dwordx4 %0, %1, off sc1" :: "v"(dst), "v"(v) : "memory");
    }
    asm volatile("s_waitcnt vmcnt(0)" ::: "memory");   // init data at LLC
    __syncthreads();
    if (tid == 0)
        __hip_atomic_store(&flags[blk << 5], 1u, __ATOMIC_RELAXED, __HIP_MEMORY_SCOPE_AGENT);

    f32x4 skip_acc[4][2];
    #pragma unroll
    for (int mt = 0; mt < 4; ++mt)
        #pragma unroll
        for (int nt = 0; nt < 2; ++nt)
            skip_acc[mt][nt] = (f32x4){0.0f, 0.0f, 0.0f, 0.0f};

    float* Hin = HA;
    float* Hout = HB;

    #pragma unroll 1
    for (int i = 0; i < NLAYERS; ++i) {
        const int d = 1 << (i >= 10 ? i - 10 : i);
        const int dprev = (i == 0) ? 0 : (1 << ((i - 1) >= 10 ? i - 11 : i - 1));
        const int nleft = (d + 127) >> 7;              // producers needed (<=4)
        const int nright = (dprev + 127) >> 7;         // anti-dep readers (<=4; 0 at i=0)

        // ---- wait for neighbor progress (relaxed polls of LLC; no fences needed)
        if (w == 0) {
            int nb = -1;
            if (l < 4) { int k = l + 1; if (k <= nleft) nb = blk - k; }
            else if (l < 8) { int k = l - 3; if (k <= nright) nb = blk + k; }
            if (nb >= 0 && nb < NBLOCKS) {
                unsigned tgt = (unsigned)(i + 1);
                while (__hip_atomic_load(&flags[nb << 5], __ATOMIC_RELAXED,
                                         __HIP_MEMORY_SCOPE_AGENT) < tgt)
                    __builtin_amdgcn_s_sleep(4);
            }
        }
        __syncthreads();

        const ushort_t* PW = pbf + i * PBF_PER_LAYER;
        const float* bfb = bf_all + i * 64;
        const float* bgb = bg_all + i * 64;
        const float* brb = br_all + i * 64;
        const float* bsb = bs_all + i * 64;

        int rL[2]; rL[0] = max(tauN[0] - d, 0); rL[1] = max(tauN[1] - d, 0);

        // ---- batch-issue ALL gates H loads (sc1 -> LLC), one waitcnt.
        // "=&v" early-clobber: outputs are written while the address inputs are
        // still live for later loads in the same asm block (R5 crash lesson).
        f32x4 gA[2], gB[2], gC[2], gD[2], oA[2], oB[2], oC[2], oD[2];
        #pragma unroll
        for (int nt = 0; nt < 2; ++nt) {
            const float* pL = Hin + rL[nt] * 64 + quad * 8;
            const float* pO = Hin + tauN[nt] * 64 + quad * 8;
            asm volatile(
                "global_load_dwordx4 %0, %8, off sc1\n\t"
                "global_load_dwordx4 %1, %8, off offset:16 sc1\n\t"
                "global_load_dwordx4 %2, %8, off offset:128 sc1\n\t"
                "global_load_dwordx4 %3, %8, off offset:144 sc1\n\t"
                "global_load_dwordx4 %4, %9, off sc1\n\t"
                "global_load_dwordx4 %5, %9, off offset:16 sc1\n\t"
                "global_load_dwordx4 %6, %9, off offset:128 sc1\n\t"
                "global_load_dwordx4 %7, %9, off offset:144 sc1"
                : "=&v"(gA[nt]), "=&v"(gB[nt]), "=&v"(gC[nt]), "=&v"(gD[nt]),
                  "=&v"(oA[nt]), "=&v"(oB[nt]), "=&v"(oC[nt]), "=&v"(oD[nt])
                : "v"(pL), "v"(pO) : "memory");
        }
        asm volatile("s_waitcnt vmcnt(0)" ::: "memory");
        __builtin_amdgcn_sched_barrier(0);             // rule #18: pin uses after the wait

        bf16x8 bl[4][2];
        #pragma unroll
        for (int nt = 0; nt < 2; ++nt) {
            bl[0][nt] = cvt8(gA[nt], gB[nt]);
            bl[1][nt] = cvt8(gC[nt], gD[nt]);
            bl[2][nt] = cvt8(oA[nt], oB[nt]);
            bl[3][nt] = cvt8(oC[nt], oD[nt]);
        }

        // ---- gates GEMM, biases folded into accumulator init
        f32x4 acc[8][2];
        #pragma unroll
        for (int mt = 0; mt < 4; ++mt) {
            f32x4 bfv = *(const f32x4*)(bfb + mt * 16 + quad * 4);
            f32x4 bgv = *(const f32x4*)(bgb + mt * 16 + quad * 4);
            acc[mt][0] = bfv; acc[mt][1] = bfv;
            acc[mt + 4][0] = bgv; acc[mt + 4][1] = bgv;
        }

        #pragma unroll
        for (int ks = 0; ks < 4; ++ks) {
            #pragma unroll
            for (int mt = 0; mt < 8; ++mt) {
                BF8 af; af.u4 = *(const uint4v*)(PW + (((mt << 2) + ks) * 64 + l) * 8);
                acc[mt][0] = __builtin_amdgcn_mfma_f32_16x16x32_bf16(af.v, bl[ks][0], acc[mt][0], 0, 0, 0);
                acc[mt][1] = __builtin_amdgcn_mfma_f32_16x16x32_bf16(af.v, bl[ks][1], acc[mt][1], 0, 0, 0);
            }
        }

        // ---- z = tanh(f)*sigmoid(g) -> ZB
        #pragma unroll
        for (int nt = 0; nt < 2; ++nt) {
            int nloc = w * 32 + nt * 16 + l15;
            #pragma unroll
            for (int mt = 0; mt < 4; ++mt) {
                u64_t pk = 0;
                #pragma unroll
                for (int r = 0; r < 4; ++r) {
                    float f = acc[mt][nt][r];
                    float g = acc[mt + 4][nt][r];
                    float e2 = __expf(2.0f * f);
                    float th = 1.0f - 2.0f / (e2 + 1.0f);
                    float sg = 1.0f / (1.0f + __expf(-g));
                    pk |= (u64_t)f2bf(th * sg) << (r * 16);
                }
                *(u64_t*)(ZB + nloc * 72 + mt * 16 + quad * 4) = pk;
            }
        }
        __syncthreads();   // orders ZB stores before 128-bit ZB reads

        // ---- res/skip GEMM, biases in acc init
        f32x4 acc2[8][2];
        #pragma unroll
        for (int mt = 0; mt < 4; ++mt) {
            f32x4 brv = *(const f32x4*)(brb + mt * 16 + quad * 4);
            f32x4 bsv = *(const f32x4*)(bsb + mt * 16 + quad * 4);
            acc2[mt][0] = brv; acc2[mt][1] = brv;
            acc2[mt + 4][0] = bsv; acc2[mt + 4][1] = bsv;
        }

        const ushort_t* PRS = PW + 16384;
        #pragma unroll
        for (int ks = 0; ks < 2; ++ks) {
            bf16x8 bfr[2];
            #pragma unroll
            for (int nt = 0; nt < 2; ++nt) {
                BF8 t; t.u4 = *(const uint4v*)(ZB + (w * 32 + nt * 16 + l15) * 72 + ks * 32 + quad * 8);
                bfr[nt] = t.v;
            }
            #pragma unroll
            for (int mt = 0; mt < 8; ++mt) {
                BF8 af; af.u4 = *(const uint4v*)(PRS + (((mt << 1) + ks) * 64 + l) * 8);
                acc2[mt][0] = __builtin_amdgcn_mfma_f32_16x16x32_bf16(af.v, bfr[0], acc2[mt][0], 0, 0, 0);
                acc2[mt][1] = __builtin_amdgcn_mfma_f32_16x16x32_bf16(af.v, bfr[1], acc2[mt][1], 0, 0, 0);
            }
        }

        // ---- epilogue: Hout = res + right (sc1); skip accumulates in registers
        #pragma unroll
        for (int nt = 0; nt < 2; ++nt) {
            int tau = tauN[nt];
            const float* hb = Hin + tau * 64 + quad * 4;
            f32x4 h0, h1, h2, h3;
            asm volatile(
                "global_load_dwordx4 %0, %4, off sc1\n\t"
                "global_load_dwordx4 %1, %4, off offset:64 sc1\n\t"
                "global_load_dwordx4 %2, %4, off offset:128 sc1\n\t"
                "global_load_dwordx4 %3, %4, off offset:192 sc1"
                : "=&v"(h0), "=&v"(h1), "=&v"(h2), "=&v"(h3)
                : "v"(hb) : "memory");
            asm volatile("s_waitcnt vmcnt(0)" ::: "memory");
            __builtin_amdgcn_sched_barrier(0);
            f32x4 hv[4] = { h0, h1, h2, h3 };
            f32x4 ov[4];
            #pragma unroll
            for (int mt = 0; mt < 4; ++mt) {
                #pragma unroll
                for (int r = 0; r < 4; ++r) {
                    ov[mt][r] = acc2[mt][nt][r] + hv[mt][r];
                    skip_acc[mt][nt][r] += acc2[mt + 4][nt][r];
                }
            }
            if (i < NLAYERS - 1) {
                float* ho = Hout + tau * 64 + quad * 4;
                asm volatile(
                    "global_store_dwordx4 %0, %1, off sc1\n\t"
                    "global_store_dwordx4 %0, %2, off offset:64 sc1\n\t"
                    "global_store_dwordx4 %0, %3, off offset:128 sc1\n\t"
                    "global_store_dwordx4 %0, %4, off offset:192 sc1"
                    :: "v"(ho), "v"(ov[0]), "v"(ov[1]), "v"(ov[2]), "v"(ov[3])
                    : "memory");
            }
        }

        // ---- publish layer completion (relaxed; sc1 data already at LLC after waitcnt)
        asm volatile("s_waitcnt vmcnt(0)" ::: "memory");
        __syncthreads();
        if (i < NLAYERS - 1 && tid == 0)
            __hip_atomic_store(&flags[blk << 5], (unsigned)(i + 2), __ATOMIC_RELAXED,
                               __HIP_MEMORY_SCOPE_AGENT);

        float* t = Hin; Hin = Hout; Hout = t;
    }

    // ---- output head (block-local: skip is in registers; no further grid syncs)
    // (the publish __syncthreads above already ordered layer-19 ZB reads)

    // Phase A: Y0 = lrelu_alpha0(skip) -> ZB rows (wave-local)
    #pragma unroll
    for (int nt = 0; nt < 2; ++nt) {
        int nloc = w * 32 + nt * 16 + l15;
        #pragma unroll
        for (int mt = 0; mt < 4; ++mt) {
            f32x4 a = *(const f32x4*)(alpha + mt * 16 + quad * 4);
            u64_t pk = 0;
            #pragma unroll
            for (int r = 0; r < 4; ++r) {
                float x = skip_acc[mt][nt][r];
                x = x > 0.0f ? x : a[r] * x;
                pk |= (u64_t)f2bf(x) << (r * 16);
            }
            *(u64_t*)(ZB + nloc * 72 + mt * 16 + quad * 4) = pk;
        }
    }
    __syncthreads();

    const ushort_t* PW0 = pbf + PBF_LAYERS;
    const ushort_t* PW1 = PW0 + 4096;

    #pragma unroll 1
    for (int nt = 0; nt < 2; ++nt) {
        int nloc = w * 32 + nt * 16 + l15;
        int zloc = w * 32 + nt * 16 + l15;

        // W0 GEMM (64x64), bias in acc init
        f32x4 acc0[4];
        #pragma unroll
        for (int mt = 0; mt < 4; ++mt) acc0[mt] = *(const f32x4*)(b_out0 + mt * 16 + quad * 4);
        #pragma unroll
        for (int ks = 0; ks < 2; ++ks) {
            BF8 t; t.u4 = *(const uint4v*)(ZB + zloc * 72 + ks * 32 + quad * 8);
            #pragma unroll
            for (int mt = 0; mt < 4; ++mt) {
                BF8 af; af.u4 = *(const uint4v*)(PW0 + (((mt << 1) + ks) * 64 + l) * 8);
                acc0[mt] = __builtin_amdgcn_mfma_f32_16x16x32_bf16(af.v, t.v, acc0[mt], 0, 0, 0);
            }
        }

        // lrelu_alpha1 -> YB (wave-local rows; YB is 64 rows, indexed w*16+l15)
        int yloc = w * 16 + l15;
        #pragma unroll
        for (int mt = 0; mt < 4; ++mt) {
            f32x4 a = *(const f32x4*)(alpha + 64 + mt * 16 + quad * 4);
            u64_t pk = 0;
            #pragma unroll
            for (int r = 0; r < 4; ++r) {
                float x = acc0[mt][r];
                x = x > 0.0f ? x : a[r] * x;
                pk |= (u64_t)f2bf(x) << (r * 16);
            }
            *(u64_t*)(YB + yloc * 72 + mt * 16 + quad * 4) = pk;
        }
        __syncthreads();

        // W1 GEMM (256x64), bias in acc init
        f32x4 acc1[16];
        #pragma unroll
        for (int mt = 0; mt < 16; ++mt) acc1[mt] = *(const f32x4*)(b_out1 + mt * 16 + quad * 4);
        #pragma unroll
        for (int ks = 0; ks < 2; ++ks) {
            BF8 t; t.u4 = *(const uint4v*)(YB + yloc * 72 + ks * 32 + quad * 8);
            #pragma unroll
            for (int mt = 0; mt < 16; ++mt) {
                BF8 af; af.u4 = *(const uint4v*)(PW1 + (((mt << 1) + ks) * 64 + l) * 8);
                acc1[mt] = __builtin_amdgcn_mfma_f32_16x16x32_bf16(af.v, t.v, acc1[mt], 0, 0, 0);
            }
        }

        int u = tau0 + nloc - OUT_START;
        if (u >= 0) {
            #pragma unroll
            for (int mt = 0; mt < 16; ++mt)
                #pragma unroll
                for (int r = 0; r < 4; ++r)
                    out[(mt * 16 + quad * 4 + r) * OUT_W + u] = acc1[mt][r];
        }
        __syncthreads();
    }
}

// ---------------------------------------------------------------- launch
extern "C" void kernel_launch(void* const* d_in, const int* in_sizes, int n_in,
                              void* d_out, int out_size, void* d_ws, size_t ws_size,
                              hipStream_t stream)
{
    const float* input  = (const float*)d_in[0];
    const float* w0     = (const float*)d_in[1];
    const float* b0     = (const float*)d_in[2];
    const float* wf     = (const float*)d_in[3];
    const float* bf     = (const float*)d_in[4];
    const float* wg     = (const float*)d_in[5];
    const float* bg     = (const float*)d_in[6];
    const float* wr     = (const float*)d_in[7];
    const float* br     = (const float*)d_in[8];
    const float* wsk    = (const float*)d_in[9];
    const float* bs     = (const float*)d_in[10];
    const float* alpha  = (const float*)d_in[11];
    const float* w_out0 = (const float*)d_in[12];
    const float* b_out0 = (const float*)d_in[13];
    const float* w_out1 = (const float*)d_in[14];
    const float* b_out1 = (const float*)d_in[15];
    float* outp = (float*)d_out;

    float* wsbase = (float*)d_ws;
    ushort_t* pbf = (ushort_t*)wsbase;
    float* HA = wsbase + H0_OFF;
    float* HB = wsbase + H1_OFF;
    unsigned* flags = (unsigned*)(wsbase + FLAG_OFF);

    pack_mfma<<<PBF_TOTAL / 256, 256, 0, stream>>>(wf, wg, wr, wsk, w_out0, w_out1, pbf, flags);

    wavenet_fused<<<dim3(NBLOCKS), dim3(256), 0, stream>>>(
        input, w0, b0, pbf, bf, bg, br, bs, alpha, b_out0, b_out1,
        HA, HB, outp, flags);
}